// Round 9
// baseline (297.170 us; speedup 1.0000x reference)
//
#include <hip/hip_runtime.h>

#define B_ 8
#define C_ 96
#define CP_ 104   // padded channels: 208 B/point; pad never read by MFMA (k<96)
#define M_ 4096
#define K_ 9

typedef _Float16 f16x8 __attribute__((ext_vector_type(8)));
typedef float f32x4 __attribute__((ext_vector_type(4)));

typedef const __attribute__((address_space(1))) unsigned int* as1_u32p;
typedef __attribute__((address_space(3))) unsigned int* as3_u32p;

__device__ inline void g2lds16(const void* g, void* l) {
  __builtin_amdgcn_global_load_lds((as1_u32p)g, (as3_u32p)l, 16, 0, 0);
}

// full list-insert (assumes dv < tmax already checked)
#define INSERT(dv, nv) do {                                                   \
    const int pz_ = tpos;                                                     \
    _Pragma("unroll")                                                         \
    for (int k_ = 0; k_ < K_; ++k_) if (k_ == pz_) { tv[k_] = (dv); ti[k_] = (nv); } \
    float mx_ = tv[0]; int mp_ = 0;                                           \
    _Pragma("unroll")                                                         \
    for (int k_ = 1; k_ < K_; ++k_) if (tv[k_] > mx_) { mx_ = tv[k_]; mp_ = k_; } \
    tmax = mx_; tpos = mp_;                                                   \
  } while (0)

// ---------------------------------------------------------------------------
// prep1: per-point squared norm + fp16 split (hi = f16(x), lo = f16(x - hi))
// written point-major [B][M][CP_] so MFMA fragments & staging are linear.
// (unchanged from the r6/r7 passing kernel)
// ---------------------------------------------------------------------------
__global__ __launch_bounds__(256) void prep1_kernel(
    const float* __restrict__ x, float* __restrict__ sq,
    unsigned short* __restrict__ xhi, unsigned short* __restrict__ xlo) {
  __shared__ float Xt[C_][64];
  const int b = blockIdx.y, m0 = blockIdx.x * 64, tid = threadIdx.x;
  const float* xb = x + (size_t)b * C_ * M_;
  for (int i = tid; i < C_ * 16; i += 256) {
    int c = i >> 4, j4 = (i & 15) << 2;
    *(float4*)&Xt[c][j4] = *(const float4*)&xb[(size_t)c * M_ + m0 + j4];
  }
  __syncthreads();
  if (tid < 64) {
    float s = 0.f;
#pragma unroll
    for (int c = 0; c < C_; ++c) { float v = Xt[c][tid]; s += v * v; }
    sq[b * M_ + m0 + tid] = s;
  }
  const int p = tid & 63, part = tid >> 6;  // thread owns point p, 24 channels
  union { unsigned short u[24]; uint4 q[3]; } hb, lb;
#pragma unroll
  for (int i = 0; i < 24; ++i) {
    float v = Xt[part * 24 + i][p];
    _Float16 h = (_Float16)v;
    _Float16 l = (_Float16)(v - (float)h);
    hb.u[i] = __builtin_bit_cast(unsigned short, h);
    lb.u[i] = __builtin_bit_cast(unsigned short, l);
  }
  size_t base = ((size_t)b * M_ + m0 + p) * CP_ + part * 24;
#pragma unroll
  for (int i = 0; i < 3; ++i) {
    *(uint4*)&xhi[base + i * 8] = hb.q[i];
    *(uint4*)&xlo[base + i * 8] = lb.q[i];
  }
}

// ---------------------------------------------------------------------------
// knn v2: SWAPPED-OPERAND Gram. mfma(A=neighbor frag from LDS, B=query frag
// resident in regs) -> lane (fp,kg) holds D[neighbor kg*4+r][query fp]:
// selection runs directly on acc registers (no Dt LDS round-trip, ONE barrier
// per tile). Double-buffered global_load_lds staging (r6/r7-proven). 3-pass
// fp16-split (nh*qh + nh*ql + nl*qh). 53.8 KB LDS -> 3 blocks/CU.
// ---------------------------------------------------------------------------
__global__ __launch_bounds__(256, 3) void knn_kernel(
    const unsigned short* __restrict__ xhi, const unsigned short* __restrict__ xlo,
    const float* __restrict__ sq, int* __restrict__ idxw) {
  __shared__ struct { unsigned short bhi[64 * CP_]; unsigned short blo[64 * CP_]; } S[2]; // 53248 B
  __shared__ float sqc[2][64];                                                           // 512 B
  const int b = blockIdx.y, r0 = blockIdx.x * 64, tid = threadIdx.x;
  const int lane = tid & 63, w = tid >> 6;
  const int fp = lane & 15, kg = lane >> 4;
  const size_t bm = (size_t)b * M_;

  // ---- resident QUERY fragments (B operand): query q = r0 + w*16 + fp ----
  // B layout for 16x16x32: col = lane&15, k-slice = (lane>>4)*8  (same per-lane
  // addressing as the A layout -> identical load math).
  f16x8 qhi[3], qlo[3];
#pragma unroll
  for (int kt = 0; kt < 3; ++kt) {
    size_t off = (bm + r0 + w * 16 + fp) * CP_ + kt * 32 + kg * 8;
    qhi[kt] = *(const f16x8*)&xhi[off];
    qlo[kt] = *(const f16x8*)&xlo[off];
  }

  float tv[K_]; int ti[K_]; float tmax = 3.4e38f; int tpos = 0;
#pragma unroll
  for (int k = 0; k < K_; ++k) { tv[k] = 3.4e38f; ti[k] = 0; }

  auto stage = [&](int n0, int pp) {
    const unsigned short* sh = xhi + (bm + n0) * CP_;
    const unsigned short* sl = xlo + (bm + n0) * CP_;
    unsigned short* dh = S[pp].bhi;
    unsigned short* dl = S[pp].blo;
#pragma unroll
    for (int it = 0; it < 3; ++it) {
      int ch = tid + it * 256;                 // 16B chunk index (832 total)
      g2lds16(sh + ch * 8, dh + ch * 8);
      g2lds16(sl + ch * 8, dl + ch * 8);
    }
    if (tid < 64) {
      int ch = 768 + tid;
      g2lds16(sh + ch * 8, dh + ch * 8);
      g2lds16(sl + ch * 8, dl + ch * 8);
      sqc[pp][tid] = sq[bm + n0 + tid];
    }
  };

  stage(0, 0);
  for (int t = 0; t < 64; ++t) {
    const int n0 = t * 64;
    const int cur = t & 1;
    __syncthreads();   // stage(t) drained (vmcnt(0) before barrier); S[cur^1] free
    if (t < 63) stage(n0 + 64, cur ^ 1);   // DMA overlaps compute below

    // cap-2 deferred-insert buffer spans the whole tile (16 candidates)
    float b0d = 0.f, b1d = 0.f; int b0n = 0, b1n = 0, bcnt = 0;

#pragma unroll
    for (int rs = 0; rs < 4; ++rs) {
      // A fragment: neighbor rows rs*16+fp, k-slice kg*8 (row stride 208 B ->
      // 8 accesses/bank exactly = no conflict penalty)
      f16x8 nh[3], nl[3];
#pragma unroll
      for (int kt = 0; kt < 3; ++kt) {
        int boff = (rs * 16 + fp) * CP_ + kt * 32 + kg * 8;
        nh[kt] = *(const f16x8*)&S[cur].bhi[boff];
        nl[kt] = *(const f16x8*)&S[cur].blo[boff];
      }
      f32x4 acc = {0.f, 0.f, 0.f, 0.f};
#pragma unroll
      for (int kt = 0; kt < 3; ++kt) {
        acc = __builtin_amdgcn_mfma_f32_16x16x32_f16(nh[kt], qhi[kt], acc, 0, 0, 0);
        acc = __builtin_amdgcn_mfma_f32_16x16x32_f16(nh[kt], qlo[kt], acc, 0, 0, 0);
        acc = __builtin_amdgcn_mfma_f32_16x16x32_f16(nl[kt], qhi[kt], acc, 0, 0, 0);
      }
      // D: col=lane&15 (our query), row=(lane>>4)*4+r (neighbor in chunk rs)
#pragma unroll
      for (int r = 0; r < 4; ++r) {
        const int nrow = rs * 16 + kg * 4 + r;
        const float d = sqc[cur][nrow] - 2.f * acc[r];   // broadcast LDS read
        if (d < tmax) {
          const int n = n0 + nrow;
          if (bcnt == 2) {
            if (b0d < tmax) INSERT(b0d, b0n);   // recheck: tmax may have tightened
            b0d = b1d; b0n = b1n;
            b1d = d;   b1n = n;
          } else if (bcnt == 1) {
            b1d = d; b1n = n; bcnt = 2;
          } else {
            b0d = d; b0n = n; bcnt = 1;
          }
        }
      }
    }
    // end-of-tile drain (recheck each; b0 is older)
    if (bcnt >= 1 && b0d < tmax) INSERT(b0d, b0n);
    if (bcnt == 2 && b1d < tmax) INSERT(b1d, b1n);
  }

  // ---- merge: 4 lane-lists (kg) per query row (stride 37) ----
  __syncthreads();                          // staging LDS dead; reuse as merge buf
  float* mv = (float*)&S[0];
  int*   mi = (int*)((char*)&S[0] + 64 * 37 * 4);
  const int qrow = w * 16 + fp;             // query row within block
#pragma unroll
  for (int k = 0; k < K_; ++k) {
    mv[qrow * 37 + kg * K_ + k] = tv[k];
    mi[qrow * 37 + kg * K_ + k] = ti[k];
  }
  __syncthreads();
  if (tid < 64) {
    float fv[K_]; int fi[K_];
    float mx = 3.4e38f; int mp = 0;
#pragma unroll
    for (int k = 0; k < K_; ++k) { fv[k] = 3.4e38f; fi[k] = 0; }
    for (int s = 0; s < 36; ++s) {
      float v = mv[tid * 37 + s]; int id = mi[tid * 37 + s];
      if (v < mx) {
#pragma unroll
        for (int k = 0; k < K_; ++k) if (k == mp) { fv[k] = v; fi[k] = id; }
        float m2 = fv[0]; int p2 = 0;
#pragma unroll
        for (int k = 1; k < K_; ++k) if (fv[k] > m2) { m2 = fv[k]; p2 = k; }
        mx = m2; mp = p2;
      }
    }
#pragma unroll
    for (int k = 0; k < K_; ++k)
      idxw[((size_t)b * M_ + r0 + tid) * K_ + k] = fi[k];
  }
}

// ---------------------------------------------------------------------------
// prep2: P/Q projection GEMM (runs AFTER knn; reuses the dead xhi/xlo region).
//   P[m] = x_m @ (W1[0:C] - W1[C:2C]) + b1,  Q[m] = x_m @ W1[C:2C]
// ---------------------------------------------------------------------------
__global__ __launch_bounds__(256) void prep2_kernel(
    const float* __restrict__ x, const float* __restrict__ W1,
    const float* __restrict__ b1, float* __restrict__ P, float* __restrict__ Q) {
  __shared__ float Xt[C_][64];
  __shared__ float Wt[C_][64];
  const int b = blockIdx.y, m0 = blockIdx.x * 64;
  const int tid = threadIdx.x;
  const float* xb = x + (size_t)b * C_ * M_;

  for (int i = tid; i < C_ * 16; i += 256) {
    int c = i >> 4, j4 = (i & 15) << 2;
    *(float4*)&Xt[c][j4] = *(const float4*)&xb[(size_t)c * M_ + m0 + j4];
  }

  const int ty = tid >> 4, tx = tid & 15;
  for (int t = 0; t < 3; ++t) {
    const int u0 = t * 64;
    __syncthreads();
    for (int i = tid; i < C_ * 64; i += 256) {
      int cin = i >> 6, j = i & 63;
      int u = u0 + j;
      float wv;
      if (u < C_) wv = W1[cin * C_ + u] - W1[(C_ + cin) * C_ + u];
      else        wv = W1[(C_ + cin) * C_ + (u - C_)];
      Wt[cin][j] = wv;
    }
    __syncthreads();
    float acc[4][4] = {};
#pragma unroll 8
    for (int c = 0; c < C_; ++c) {
      float4 rr = *(const float4*)&Xt[c][ty << 2];
      float4 ww = *(const float4*)&Wt[c][tx << 2];
      acc[0][0] += rr.x * ww.x; acc[0][1] += rr.x * ww.y; acc[0][2] += rr.x * ww.z; acc[0][3] += rr.x * ww.w;
      acc[1][0] += rr.y * ww.x; acc[1][1] += rr.y * ww.y; acc[1][2] += rr.y * ww.z; acc[1][3] += rr.y * ww.w;
      acc[2][0] += rr.z * ww.x; acc[2][1] += rr.z * ww.y; acc[2][2] += rr.z * ww.z; acc[2][3] += rr.z * ww.w;
      acc[3][0] += rr.w * ww.x; acc[3][1] += rr.w * ww.y; acc[3][2] += rr.w * ww.z; acc[3][3] += rr.w * ww.w;
    }
#pragma unroll
    for (int i = 0; i < 4; ++i) {
      int m = m0 + (ty << 2) + i;
      size_t base = ((size_t)b * M_ + m) * C_;
#pragma unroll
      for (int j = 0; j < 4; ++j) {
        int u = u0 + (tx << 2) + j;
        float v = acc[i][j];
        if (u < C_) P[base + u] = v + b1[u];
        else        Q[base + (u - C_)] = v;
      }
    }
  }
}

// ---------------------------------------------------------------------------
// edge_mlp: g[m] = mean_k LReLU(P[m] + Q[idx[m,k]]); out = relu(g @ W2 + b2).
// ---------------------------------------------------------------------------
__global__ __launch_bounds__(256) void edge_mlp_kernel(
    const float* __restrict__ P, const float* __restrict__ Q,
    const int* __restrict__ idxw, const float* __restrict__ W2,
    const float* __restrict__ b2, float* __restrict__ out) {
  __shared__ float g_l[C_][64];
  __shared__ float W2t[C_ * C_];
  const int b = blockIdx.y, m0 = blockIdx.x * 64;
  const int tid = threadIdx.x;

  for (int i = tid; i < (C_ * C_) / 4; i += 256)
    *(float4*)&W2t[i * 4] = *(const float4*)&W2[i * 4];

  const int ml = tid & 63, cg = tid >> 6;
  const int m = m0 + ml;
  const float* prow = P + ((size_t)b * M_ + m) * C_ + cg * 24;
  float pr[24];
#pragma unroll
  for (int t = 0; t < 24; t += 4) {
    float4 v = *(const float4*)(prow + t);
    pr[t] = v.x; pr[t + 1] = v.y; pr[t + 2] = v.z; pr[t + 3] = v.w;
  }
  float gacc[24] = {};
  const int* irow = idxw + ((size_t)b * M_ + m) * K_;
#pragma unroll
  for (int k = 0; k < K_; ++k) {
    int j = irow[k];
    const float* qrow = Q + ((size_t)b * M_ + j) * C_ + cg * 24;
#pragma unroll
    for (int t = 0; t < 24; t += 4) {
      float4 qv = *(const float4*)(qrow + t);
      float h;
      h = pr[t + 0] + qv.x; gacc[t + 0] += (h >= 0.f) ? h : 0.01f * h;
      h = pr[t + 1] + qv.y; gacc[t + 1] += (h >= 0.f) ? h : 0.01f * h;
      h = pr[t + 2] + qv.z; gacc[t + 2] += (h >= 0.f) ? h : 0.01f * h;
      h = pr[t + 3] + qv.w; gacc[t + 3] += (h >= 0.f) ? h : 0.01f * h;
    }
  }
#pragma unroll
  for (int t = 0; t < 24; ++t) g_l[cg * 24 + t][ml] = gacc[t] * (1.f / 9.f);
  __syncthreads();

  const int ty = tid >> 4, tx = tid & 15;
  float acc2[4][6] = {};
#pragma unroll 4
  for (int c = 0; c < C_; ++c) {
    float4 rr = *(const float4*)&g_l[c][ty << 2];
    float2 wa = *(const float2*)&W2t[c * C_ + tx * 6];
    float2 wb = *(const float2*)&W2t[c * C_ + tx * 6 + 2];
    float2 wc = *(const float2*)&W2t[c * C_ + tx * 6 + 4];
    float rv[4] = {rr.x, rr.y, rr.z, rr.w};
    float wv[6] = {wa.x, wa.y, wb.x, wb.y, wc.x, wc.y};
#pragma unroll
    for (int i = 0; i < 4; ++i)
#pragma unroll
      for (int j = 0; j < 6; ++j) acc2[i][j] += rv[i] * wv[j];
  }
#pragma unroll
  for (int i = 0; i < 4; ++i) {
    int mm = m0 + (ty << 2) + i;
#pragma unroll
    for (int j = 0; j < 6; ++j) {
      int u = tx * 6 + j;
      float v = acc2[i][j] + b2[u];
      v = fmaxf(v, 0.f);
      out[((size_t)b * C_ + u) * M_ + mm] = v;
    }
  }
}

extern "C" void kernel_launch(void* const* d_in, const int* in_sizes, int n_in,
                              void* d_out, int out_size, void* d_ws, size_t ws_size,
                              hipStream_t stream) {
  const float* x  = (const float*)d_in[0];
  const float* W1 = (const float*)d_in[1];
  const float* b1 = (const float*)d_in[2];
  const float* W2 = (const float*)d_in[3];
  const float* b2 = (const float*)d_in[4];
  float* out = (float*)d_out;

  // ws layout — peak 26,476,544 B (proven footprint; do NOT grow):
  //   [0,        131072)    sq
  //   [131072,   1310720)   idxw
  //   phase 1 (prep1+knn):  xhi [1310720, 8126464), xlo [8126464, 14942208)
  //   phase 2 (prep2+mlp):  P   [1310720, 13893632), Q  [13893632, 26476544)
  //   (P/Q alias the dead xhi/xlo region; kernels are stream-ordered)
  char* ws = (char*)d_ws;
  float* sq  = (float*)ws;
  int* idxw  = (int*)(ws + 131072);
  unsigned short* xhi = (unsigned short*)(ws + 1310720);
  unsigned short* xlo = (unsigned short*)(ws + 8126464);
  float* P = (float*)(ws + 1310720);
  float* Q = (float*)(ws + 13893632);

  dim3 grid(M_ / 64, B_), blk(256);
  prep1_kernel<<<grid, blk, 0, stream>>>(x, sq, xhi, xlo);
  knn_kernel<<<grid, blk, 0, stream>>>(xhi, xlo, sq, idxw);
  prep2_kernel<<<grid, blk, 0, stream>>>(x, W1, b1, P, Q);
  edge_mlp_kernel<<<grid, blk, 0, stream>>>(P, Q, idxw, W2, b2, out);
}